// Round 2
// baseline (841.586 us; speedup 1.0000x reference)
//
#include <hip/hip_runtime.h>
#include <cmath>

// UOT Bregman ADMM (badmm-e), B=64, N=1024, D=512, NUM=4 iterations. f32.
//
// Structural algebra: z1 = zC(b,d) - zD(b,n) stays separable because the
// broadcast parts cancel under y - lse(y, axis): log_mu is (B,D)-only,
// log_eta is (B,N)-only for ALL iterations; sum_t/sum_s are never needed.
// Full (B,N,D) tensors: x (input), y'/log_s (one shared buffer), z.
//
// Live-path schedule (dead code across iterations removed):
//   k=0..2: K1(row: step T + write y') -> K2a(col lse partials of y')
//           -> K2b(finish step S: log_s, z update) -> small(mu/eta updates)
//   k=3:    K1 only, writes exp(log_t)*mask to d_out.

#define B_ 64
#define N_ 1024
#define D_ 512
#define EPS_ 1e-8f
#define NCHUNK 8
#define CH (N_ / NCHUNK)     // 128 rows per column chunk
#define NCOL (B_ * D_)       // 32768 columns
static const size_t NT_ = (size_t)B_ * N_ * D_;   // 33,554,432

__device__ __forceinline__ float wmax64(float v) {
#pragma unroll
  for (int o = 32; o > 0; o >>= 1) v = fmaxf(v, __shfl_xor(v, o, 64));
  return v;
}
__device__ __forceinline__ float wsum64(float v) {
#pragma unroll
  for (int o = 32; o > 0; o >>= 1) v += __shfl_xor(v, o, 64);
  return v;
}
__device__ __forceinline__ void olse(float& m, float& s, float v) {
  float nm = fmaxf(m, v);
  s = s * __expf(m - nm) + __expf(v - nm);
  m = nm;
}

// ---------------------------------------------------------------------------
// K1: one wave per (b,n) row, 8 elems/lane over D=512.
// Step T: y=(x-z)/rho+log_s; lse over D; log_t = (log_mu - lse) + y.
// Writes y' = (z + rho*log_t)/(a1+rho) into the SAME buffer log_s was read
// from (same-thread same-element read-then-write: safe).
// LAST: writes exp(log_t)*mask to outv instead.
// ---------------------------------------------------------------------------
template <int IS_FIRST, int LAST>
__global__ __launch_bounds__(256) void k1_row(
    const float* __restrict__ x, const float* __restrict__ p0,
    const float* __restrict__ q0, const float* __restrict__ mask,
    const float* __restrict__ a1arr, const float* __restrict__ rhoarr,
    const int k, const float* __restrict__ mun,
    float* ys,                          // log_s_{k-1} (read) / y'_k (write)
    const float* __restrict__ z, float* __restrict__ outv)
{
  const int wid  = threadIdx.x >> 6;
  const int lane = threadIdx.x & 63;
  const int row  = (blockIdx.x << 2) + wid;   // [0, B*N)
  const int b    = row >> 10;                 // N = 1024
  const float rho = rhoarr[k];
  const float inv_rho = 1.0f / rho;
  const size_t base = (size_t)row * D_ + (size_t)(lane * 8);
  const int pb = (b << 9) + lane * 8;

  float xv[8], y[8], lmu[8], zv[8];
  *(float4*)&xv[0] = *(const float4*)&x[base];
  *(float4*)&xv[4] = *(const float4*)&x[base + 4];

  if (IS_FIRST) {
    float pv[8];
    *(float4*)&pv[0] = *(const float4*)&p0[pb];
    *(float4*)&pv[4] = *(const float4*)&p0[pb + 4];
    const float q0v = q0[row];
#pragma unroll
    for (int j = 0; j < 8; ++j) {
      lmu[j] = __logf(pv[j]);                       // log_mu init = log(p0)
      float lsv = __logf(q0v * pv[j] + EPS_);       // log_s init
      y[j] = xv[j] * inv_rho + lsv;
      zv[j] = 0.f;
    }
  } else {
    float lsv[8];
    *(float4*)&zv[0]  = *(const float4*)&z[base];
    *(float4*)&zv[4]  = *(const float4*)&z[base + 4];
    *(float4*)&lsv[0] = *(const float4*)&ys[base];
    *(float4*)&lsv[4] = *(const float4*)&ys[base + 4];
    *(float4*)&lmu[0] = *(const float4*)&mun[pb];
    *(float4*)&lmu[4] = *(const float4*)&mun[pb + 4];
#pragma unroll
    for (int j = 0; j < 8; ++j) y[j] = (xv[j] - zv[j]) * inv_rho + lsv[j];
  }

  float mloc = -INFINITY;
#pragma unroll
  for (int j = 0; j < 8; ++j) mloc = fmaxf(mloc, y[j]);
  const float m = wmax64(mloc);
  float sloc = 0.f;
#pragma unroll
  for (int j = 0; j < 8; ++j) sloc += __expf(y[j] - m);
  const float lse = m + __logf(wsum64(sloc));

  if (LAST) {
    const float mv = mask[row];
    float o[8];
#pragma unroll
    for (int j = 0; j < 8; ++j) o[j] = __expf(lmu[j] - lse + y[j]) * mv;
    *(float4*)&outv[base]     = *(float4*)&o[0];
    *(float4*)&outv[base + 4] = *(float4*)&o[4];
  } else {
    const float inv_sc = 1.0f / (a1arr[k] + rho);
    float yp[8];
#pragma unroll
    for (int j = 0; j < 8; ++j)
      yp[j] = (zv[j] + rho * (lmu[j] - lse + y[j])) * inv_sc;
    *(float4*)&ys[base]     = *(float4*)&yp[0];
    *(float4*)&ys[base + 4] = *(float4*)&yp[4];
  }
}

// ---------------------------------------------------------------------------
// K2a: column lse partials of y' over N-chunks. Thread per (b,d) column.
// ---------------------------------------------------------------------------
__global__ __launch_bounds__(256) void k2a(
    const float* __restrict__ yp, float* __restrict__ pmax,
    float* __restrict__ psum)
{
  const int col = blockIdx.x * 256 + threadIdx.x;   // b*512 + d
  const int chunk = blockIdx.y;
  size_t idx = ((size_t)(col >> 9) * N_ + (size_t)(chunk * CH)) * D_ + (col & 511);
  float m0 = -INFINITY, s0 = 0.f, m1 = -INFINITY, s1 = 0.f;
  float m2 = -INFINITY, s2 = 0.f, m3 = -INFINITY, s3 = 0.f;
  for (int nn = 0; nn < CH; nn += 4) {
    float v0 = yp[idx];
    float v1 = yp[idx + D_];
    float v2 = yp[idx + 2 * D_];
    float v3 = yp[idx + 3 * D_];
    olse(m0, s0, v0); olse(m1, s1, v1); olse(m2, s2, v2); olse(m3, s3, v3);
    idx += 4 * D_;
  }
  float m = fmaxf(fmaxf(m0, m1), fmaxf(m2, m3));
  float s = s0 * __expf(m0 - m) + s1 * __expf(m1 - m) +
            s2 * __expf(m2 - m) + s3 * __expf(m3 - m);
  pmax[chunk * NCOL + col] = m;
  psum[chunk * NCOL + col] = s;
}

// ---------------------------------------------------------------------------
// K2b: finish step S. log_s = (log_eta - lse1) + y' (overwrites y' in place);
// z = z + rho*(t - s) with log_t reconstructed as (y'*(a1+rho) - z)/rho.
// ---------------------------------------------------------------------------
template <int IS_FIRST>
__global__ __launch_bounds__(256) void k2b(
    const float* __restrict__ q0, const float* __restrict__ mask,
    const float* __restrict__ a1arr, const float* __restrict__ rhoarr,
    const int k, const float* __restrict__ len,
    float* ys,                        // y' (read) / log_s (write)
    float* __restrict__ z,            // z_{k-1} (read) / z_k (write)
    const float* __restrict__ pmax, const float* __restrict__ psum)
{
  const int col = blockIdx.x * 256 + threadIdx.x;
  const int chunk = blockIdx.y;
  const float rho = rhoarr[k];
  const float sc = a1arr[k] + rho;
  const float inv_rho = 1.0f / rho;
  const float sc_ir = sc * inv_rho;

  float lse1;
  {
    float m = -INFINITY;
#pragma unroll
    for (int c = 0; c < NCHUNK; ++c) m = fmaxf(m, pmax[c * NCOL + col]);
    float s = 0.f;
#pragma unroll
    for (int c = 0; c < NCHUNK; ++c)
      s += psum[c * NCOL + col] * __expf(pmax[c * NCOL + col] - m);
    lse1 = m + __logf(s);
  }

  size_t idx = ((size_t)(col >> 9) * N_ + (size_t)(chunk * CH)) * D_ + (col & 511);
  int nrow = (col >> 9) * N_ + chunk * CH;
#pragma unroll 2
  for (int nn = 0; nn < CH; ++nn) {
    float ypv = ys[idx];
    float zv = IS_FIRST ? 0.f : z[idx];
    float le = IS_FIRST ? __logf(q0[nrow] + EPS_) : len[nrow];
    float ls = (le - lse1) + ypv;
    ys[idx] = ls;
    float mv = mask[nrow];
    float lt = IS_FIRST ? ypv * sc_ir : (ypv * sc - zv) * inv_rho;
    float t  = __expf(lt) * mv;
    float s_ = __expf(ls) * mv;
    z[idx] = zv + rho * (t - s_);
    idx += D_;
    ++nrow;
  }
}

// ---------------------------------------------------------------------------
// small: marginal updates, tiny (B,D)+(B,N) domains. blockIdx.y=0: mu task
// (per-b lse over D=512); blockIdx.y=1: eta task (per-b lse over N=1024).
// z1/z2 broadcast parts cancel under normalization -> only zC/z2C kept.
// ---------------------------------------------------------------------------
template <int K>
__global__ __launch_bounds__(256) void small_upd(
    const float* __restrict__ p0, const float* __restrict__ q0,
    const float* __restrict__ a2arr, const float* __restrict__ a3arr,
    const float* __restrict__ rhoarr,
    float* mun, float* zC, float* len, float* z2C)
{
  __shared__ float red[8];
  const int b = blockIdx.x;
  const int tid = threadIdx.x, wid = tid >> 6, lane = tid & 63;
  const float rho = rhoarr[K];

  if (blockIdx.y == 0) {
    const float a2 = a2arr[K];
    const float inv = 1.0f / (rho + a2);
    float A[2], zcv[2];
    const int i0 = b * D_ + tid;
#pragma unroll
    for (int j = 0; j < 2; ++j) {
      int i = i0 + j * 256;
      float lp = __logf(p0[i]);
      float prev = (K == 0) ? lp : mun[i];
      zcv[j] = (K == 0) ? 0.f : zC[i];
      A[j] = (rho * prev + a2 * lp - zcv[j]) * inv;
    }
    float m = wmax64(fmaxf(A[0], A[1]));
    if (lane == 0) red[wid] = m;
    __syncthreads();
    float bm = fmaxf(fmaxf(red[0], red[1]), fmaxf(red[2], red[3]));
    float s = wsum64(__expf(A[0] - bm) + __expf(A[1] - bm));
    if (lane == 0) red[4 + wid] = s;
    __syncthreads();
    float lse = bm + __logf(red[4] + red[5] + red[6] + red[7]);
#pragma unroll
    for (int j = 0; j < 2; ++j) {
      int i = i0 + j * 256;
      float mn = A[j] - lse;
      mun[i] = mn;
      if (K <= 1) zC[i] = zcv[j] + rho * __expf(mn);  // zC feeds mun_{K+1}
    }
  } else {
    const float a3 = a3arr[K];
    const float inv = 1.0f / (rho + a3);
    float E[4];
    const int i0 = b * N_ + tid * 4;
#pragma unroll
    for (int j = 0; j < 4; ++j) {
      int i = i0 + j;
      float lq = __logf(q0[i] + EPS_);
      float prev = (K == 0) ? lq : len[i];
      float z2c = (K == 0) ? 0.f : z2C[i];
      E[j] = (rho * prev + a3 * lq - z2c) * inv;
    }
    float m = wmax64(fmaxf(fmaxf(E[0], E[1]), fmaxf(E[2], E[3])));
    if (lane == 0) red[wid] = m;
    __syncthreads();
    float bm = fmaxf(fmaxf(red[0], red[1]), fmaxf(red[2], red[3]));
    float s = 0.f;
#pragma unroll
    for (int j = 0; j < 4; ++j) s += __expf(E[j] - bm);
    s = wsum64(s);
    if (lane == 0) red[4 + wid] = s;
    __syncthreads();
    float lse = bm + __logf(red[4] + red[5] + red[6] + red[7]);
#pragma unroll
    for (int j = 0; j < 4; ++j) {
      int i = i0 + j;
      float ln = E[j] - lse;
      len[i] = ln;
      if (K == 0) z2C[i] = rho * __expf(ln);          // z2C feeds len_1 only
    }
  }
}

// ---------------------------------------------------------------------------
extern "C" void kernel_launch(void* const* d_in, const int* in_sizes, int n_in,
                              void* d_out, int out_size, void* d_ws, size_t ws_size,
                              hipStream_t stream)
{
  const float* x    = (const float*)d_in[0];
  const float* p0   = (const float*)d_in[1];
  const float* q0   = (const float*)d_in[2];
  const float* a1   = (const float*)d_in[3];
  const float* a2   = (const float*)d_in[4];
  const float* a3   = (const float*)d_in[5];
  const float* rho  = (const float*)d_in[6];
  const float* mask = (const float*)d_in[7];
  float* out = (float*)d_out;

  float* ws   = (float*)d_ws;
  float* ys   = ws;                 // shared y'/log_s buffer (B,N,D)
  float* z    = ws + NT_;           // z (B,N,D)
  float* pmax = ws + 2 * NT_;       // column-lse partials (NCHUNK,NCOL)
  float* psum = pmax + (size_t)NCHUNK * NCOL;
  float* mun  = psum + (size_t)NCHUNK * NCOL;   // log_mu   (B,D)
  float* zC   = mun + (size_t)B_ * D_;          // z1 (b,d) part
  float* len  = zC  + (size_t)B_ * D_;          // log_eta  (B,N)
  float* z2C  = len + (size_t)B_ * N_;          // z2 (b,n) part

  const dim3 tb(256);
  const dim3 g1(B_ * N_ / 4);           // one wave per row
  const dim3 g2(NCOL / 256, NCHUNK);    // 128 x 8 blocks

  // ---- k = 0 ----
  k1_row<1, 0><<<g1, tb, 0, stream>>>(x, p0, q0, mask, a1, rho, 0, mun, ys, z, out);
  k2a<<<g2, tb, 0, stream>>>(ys, pmax, psum);
  k2b<1><<<g2, tb, 0, stream>>>(q0, mask, a1, rho, 0, len, ys, z, pmax, psum);
  small_upd<0><<<dim3(B_, 2), tb, 0, stream>>>(p0, q0, a2, a3, rho, mun, zC, len, z2C);

  // ---- k = 1 ----
  k1_row<0, 0><<<g1, tb, 0, stream>>>(x, p0, q0, mask, a1, rho, 1, mun, ys, z, out);
  k2a<<<g2, tb, 0, stream>>>(ys, pmax, psum);
  k2b<0><<<g2, tb, 0, stream>>>(q0, mask, a1, rho, 1, len, ys, z, pmax, psum);
  small_upd<1><<<dim3(B_, 2), tb, 0, stream>>>(p0, q0, a2, a3, rho, mun, zC, len, z2C);

  // ---- k = 2 (len_2/z2C_2 dead; mun_2 still live for k=3) ----
  k1_row<0, 0><<<g1, tb, 0, stream>>>(x, p0, q0, mask, a1, rho, 2, mun, ys, z, out);
  k2a<<<g2, tb, 0, stream>>>(ys, pmax, psum);
  k2b<0><<<g2, tb, 0, stream>>>(q0, mask, a1, rho, 2, len, ys, z, pmax, psum);
  small_upd<2><<<dim3(B_, 1), tb, 0, stream>>>(p0, q0, a2, a3, rho, mun, zC, len, z2C);

  // ---- k = 3: step T only, write exp(log_t)*mask ----
  k1_row<0, 1><<<g1, tb, 0, stream>>>(x, p0, q0, mask, a1, rho, 3, mun, ys, z, out);
}

// Round 3
// 746.764 us; speedup vs baseline: 1.1270x; 1.1270x over previous
//
#include <hip/hip_runtime.h>
#include <cmath>

// UOT Bregman ADMM (badmm-e), B=64, N=1024, D=512, NUM=4 iterations. f32.
//
// Separable-marginal algebra (verified round 2): log_mu is (B,D)-only,
// log_eta is (B,N)-only; z1/z2 broadcast parts cancel under normalization.
// Full (B,N,D) arrays: x (input), ys (y'/log_s shared), z.
//
// Round-3 changes:
//  - k1p: 1024-thread blocks (16 rows), emits column lse partials via LDS
//    -> k2a kernel eliminated (saves a full 134 MB read per iteration).
//  - kred: combines 64 chunk partials -> lse1[NCOL] (tiny).
//  - k2b: float4 x 4 columns/thread, NCHUNK=64 (CH=16) for 100% occupancy.
//  - k=2: k2b writes w = log_s - z2/rho3 and skips the z write; k1last
//    reads only (x, w)  (saves 268 MB).

#define B_ 64
#define N_ 1024
#define D_ 512
#define EPS_ 1e-8f
#define NCOL (B_ * D_)        // 32768 columns (b,d)
#define KCHUNK 64             // column-partial chunks (N/16)
#define CH2 16                // rows per k2b chunk (N/NCHUNK2)
#define NCHUNK2 64
static const size_t NT_ = (size_t)B_ * N_ * D_;   // 33,554,432

__device__ __forceinline__ float wmax64(float v) {
#pragma unroll
  for (int o = 32; o > 0; o >>= 1) v = fmaxf(v, __shfl_xor(v, o, 64));
  return v;
}
__device__ __forceinline__ float wsum64(float v) {
#pragma unroll
  for (int o = 32; o > 0; o >>= 1) v += __shfl_xor(v, o, 64);
  return v;
}

// ---------------------------------------------------------------------------
// k1p: 16 rows per block (16 waves), one wave per (b,n) row, 8 elems/lane.
// Step T: y=(x-z)/rho+log_s; row-lse; y' = (z + rho*(lmu - lse + y))/(a1+rho).
// Writes y' into ys (aliases log_s it read: same-thread read-then-write) and
// per-block column partials (max, sum-exp over the block's 16 rows).
// ---------------------------------------------------------------------------
template <int IS_FIRST>
__global__ __launch_bounds__(1024, 4) void k1p(
    const float* __restrict__ x, const float* __restrict__ p0,
    const float* __restrict__ q0,
    const float* __restrict__ a1arr, const float* __restrict__ rhoarr,
    const int k, const float* __restrict__ mun,
    float* ys,                         // log_s_{k-1} (read) / y'_k (write)
    const float* __restrict__ z,
    float* __restrict__ pmax, float* __restrict__ psum)
{
  __shared__ float lds[16 * 512];
  const int wid  = threadIdx.x >> 6;
  const int lane = threadIdx.x & 63;
  const int row  = blockIdx.x * 16 + wid;     // [0, B*N)
  const int b    = row >> 10;                 // N = 1024
  const float rho = rhoarr[k];
  const float inv_rho = 1.0f / rho;
  const float inv_sc = 1.0f / (a1arr[k] + rho);
  const size_t base = (size_t)row * D_ + (size_t)(lane * 8);
  const int pb = (b << 9) + lane * 8;

  float xv[8], y[8], lmu[8], zv[8];
  *(float4*)&xv[0] = *(const float4*)&x[base];
  *(float4*)&xv[4] = *(const float4*)&x[base + 4];

  if (IS_FIRST) {
    float pv[8];
    *(float4*)&pv[0] = *(const float4*)&p0[pb];
    *(float4*)&pv[4] = *(const float4*)&p0[pb + 4];
    const float q0v = q0[row];
#pragma unroll
    for (int j = 0; j < 8; ++j) {
      lmu[j] = __logf(pv[j]);                  // log_mu init
      float lsv = __logf(q0v * pv[j] + EPS_);  // log_s init
      y[j] = xv[j] * inv_rho + lsv;
      zv[j] = 0.f;
    }
  } else {
    *(float4*)&zv[0] = *(const float4*)&z[base];
    *(float4*)&zv[4] = *(const float4*)&z[base + 4];
    *(float4*)&y[0]  = *(const float4*)&ys[base];    // log_s
    *(float4*)&y[4]  = *(const float4*)&ys[base + 4];
    *(float4*)&lmu[0] = *(const float4*)&mun[pb];
    *(float4*)&lmu[4] = *(const float4*)&mun[pb + 4];
#pragma unroll
    for (int j = 0; j < 8; ++j) y[j] = (xv[j] - zv[j]) * inv_rho + y[j];
  }

  float mloc = -INFINITY;
#pragma unroll
  for (int j = 0; j < 8; ++j) mloc = fmaxf(mloc, y[j]);
  const float m = wmax64(mloc);
  float sloc = 0.f;
#pragma unroll
  for (int j = 0; j < 8; ++j) sloc += __expf(y[j] - m);
  const float lse = m + __logf(wsum64(sloc));

  float yp[8];
#pragma unroll
  for (int j = 0; j < 8; ++j)
    yp[j] = (zv[j] + rho * (lmu[j] - lse + y[j])) * inv_sc;
  *(float4*)&ys[base]     = *(float4*)&yp[0];
  *(float4*)&ys[base + 4] = *(float4*)&yp[4];

  // stage y' to LDS, reduce 16 rows per column
  const int dbase = lane * 8;
#pragma unroll
  for (int j = 0; j < 8; ++j) lds[wid * 512 + dbase + j] = yp[j];
  __syncthreads();
  if (threadIdx.x < 512) {
    const int d = threadIdx.x;
    float v[16];
#pragma unroll
    for (int w = 0; w < 16; ++w) v[w] = lds[w * 512 + d];
    float mm = v[0];
#pragma unroll
    for (int w = 1; w < 16; ++w) mm = fmaxf(mm, v[w]);
    float ss = 0.f;
#pragma unroll
    for (int w = 0; w < 16; ++w) ss += __expf(v[w] - mm);
    const int bb = blockIdx.x >> 6;        // 64 blocks per b
    const int chunk = blockIdx.x & 63;
    const int col = (bb << 9) + d;
    pmax[chunk * NCOL + col] = mm;
    psum[chunk * NCOL + col] = ss;
  }
}

// ---------------------------------------------------------------------------
// kred: combine 64 chunk partials per column -> lse1[NCOL].
// ---------------------------------------------------------------------------
__global__ __launch_bounds__(256) void kred(
    const float* __restrict__ pmax, const float* __restrict__ psum,
    float* __restrict__ lse1)
{
  const int col = blockIdx.x * 256 + threadIdx.x;
  float m0 = -INFINITY, m1 = -INFINITY, m2 = -INFINITY, m3 = -INFINITY;
#pragma unroll
  for (int c = 0; c < KCHUNK; c += 4) {
    m0 = fmaxf(m0, pmax[(c + 0) * NCOL + col]);
    m1 = fmaxf(m1, pmax[(c + 1) * NCOL + col]);
    m2 = fmaxf(m2, pmax[(c + 2) * NCOL + col]);
    m3 = fmaxf(m3, pmax[(c + 3) * NCOL + col]);
  }
  const float M = fmaxf(fmaxf(m0, m1), fmaxf(m2, m3));
  float s0 = 0.f, s1 = 0.f, s2 = 0.f, s3 = 0.f;
#pragma unroll
  for (int c = 0; c < KCHUNK; c += 4) {
    s0 += psum[(c + 0) * NCOL + col] * __expf(pmax[(c + 0) * NCOL + col] - M);
    s1 += psum[(c + 1) * NCOL + col] * __expf(pmax[(c + 1) * NCOL + col] - M);
    s2 += psum[(c + 2) * NCOL + col] * __expf(pmax[(c + 2) * NCOL + col] - M);
    s3 += psum[(c + 3) * NCOL + col] * __expf(pmax[(c + 3) * NCOL + col] - M);
  }
  lse1[col] = M + __logf((s0 + s1) + (s2 + s3));
}

// ---------------------------------------------------------------------------
// k2b: finish step S, float4 over 4 columns per thread.
// log_s = (log_eta - lse1) + y'   (overwrites y' in place)
// z     = z + rho*(t - s),  t from reconstruction lt = (y'*(a1+rho) - z)/rho.
// FOLD (k=2): write w = log_s - z_new/rho_{k+1} instead of log_s; no z write.
// ---------------------------------------------------------------------------
template <int IS_FIRST, int WRITE_Z, int FOLD>
__global__ __launch_bounds__(256) void k2b(
    const float* __restrict__ q0, const float* __restrict__ mask,
    const float* __restrict__ a1arr, const float* __restrict__ rhoarr,
    const int k, const float* __restrict__ len,
    float* ys,                        // y' (read) / log_s or w (write)
    float* __restrict__ z,
    const float* __restrict__ lse1)
{
  const int t4 = (blockIdx.x * 256 + threadIdx.x) * 4;   // column base
  const int b = t4 >> 9;
  const int d = t4 & 511;
  const int n0 = blockIdx.y * CH2;
  const float rho = rhoarr[k];
  const float sc = a1arr[k] + rho;
  const float inv_rho = 1.0f / rho;
  const float sc_ir = sc * inv_rho;
  const float irn = FOLD ? (1.0f / rhoarr[k + 1]) : 0.0f;

  float L[4];
  *(float4*)L = *(const float4*)&lse1[t4];

  size_t idx = ((size_t)b * N_ + (size_t)n0) * D_ + d;
  int nrow = b * N_ + n0;
#pragma unroll 4
  for (int nn = 0; nn < CH2; ++nn) {
    float ypv[4], zv[4];
    *(float4*)ypv = *(const float4*)&ys[idx];
    if (IS_FIRST) {
#pragma unroll
      for (int j = 0; j < 4; ++j) zv[j] = 0.f;
    } else {
      *(float4*)zv = *(const float4*)&z[idx];
    }
    const float le = IS_FIRST ? __logf(q0[nrow] + EPS_) : len[nrow];
    const float mv = mask[nrow];
    float wout[4], zn[4];
#pragma unroll
    for (int j = 0; j < 4; ++j) {
      float ls = (le - L[j]) + ypv[j];
      float lt = IS_FIRST ? ypv[j] * sc_ir : (ypv[j] * sc - zv[j]) * inv_rho;
      float t_ = __expf(lt) * mv;
      float s_ = __expf(ls) * mv;
      zn[j] = zv[j] + rho * (t_ - s_);
      wout[j] = FOLD ? (ls - zn[j] * irn) : ls;
    }
    *(float4*)&ys[idx] = *(float4*)wout;
    if (WRITE_Z) *(float4*)&z[idx] = *(float4*)zn;
    idx += D_;
    ++nrow;
  }
}

// ---------------------------------------------------------------------------
// k1last (k=3): out = exp(lmu - lse_row(y) + y) * mask, y = x/rho + w.
// ---------------------------------------------------------------------------
__global__ __launch_bounds__(256) void k1last(
    const float* __restrict__ x, const float* __restrict__ mask,
    const float* __restrict__ rhoarr, const float* __restrict__ mun,
    const float* __restrict__ w, float* __restrict__ outv)
{
  const int wid  = threadIdx.x >> 6;
  const int lane = threadIdx.x & 63;
  const int row  = (blockIdx.x << 2) + wid;
  const int b    = row >> 10;
  const float inv_rho = 1.0f / rhoarr[3];
  const size_t base = (size_t)row * D_ + (size_t)(lane * 8);
  const int pb = (b << 9) + lane * 8;

  float xv[8], y[8], lmu[8];
  *(float4*)&xv[0] = *(const float4*)&x[base];
  *(float4*)&xv[4] = *(const float4*)&x[base + 4];
  *(float4*)&y[0]  = *(const float4*)&w[base];
  *(float4*)&y[4]  = *(const float4*)&w[base + 4];
  *(float4*)&lmu[0] = *(const float4*)&mun[pb];
  *(float4*)&lmu[4] = *(const float4*)&mun[pb + 4];
#pragma unroll
  for (int j = 0; j < 8; ++j) y[j] = xv[j] * inv_rho + y[j];

  float mloc = -INFINITY;
#pragma unroll
  for (int j = 0; j < 8; ++j) mloc = fmaxf(mloc, y[j]);
  const float m = wmax64(mloc);
  float sloc = 0.f;
#pragma unroll
  for (int j = 0; j < 8; ++j) sloc += __expf(y[j] - m);
  const float lse = m + __logf(wsum64(sloc));

  const float mv = mask[row];
  float o[8];
#pragma unroll
  for (int j = 0; j < 8; ++j) o[j] = __expf(lmu[j] - lse + y[j]) * mv;
  *(float4*)&outv[base]     = *(float4*)&o[0];
  *(float4*)&outv[base + 4] = *(float4*)&o[4];
}

// ---------------------------------------------------------------------------
// small: marginal updates (verified round 2). blockIdx.y=0: mu (lse over D);
// blockIdx.y=1: eta (lse over N). Broadcast parts cancel -> zC/z2C only.
// ---------------------------------------------------------------------------
template <int K>
__global__ __launch_bounds__(256) void small_upd(
    const float* __restrict__ p0, const float* __restrict__ q0,
    const float* __restrict__ a2arr, const float* __restrict__ a3arr,
    const float* __restrict__ rhoarr,
    float* mun, float* zC, float* len, float* z2C)
{
  __shared__ float red[8];
  const int b = blockIdx.x;
  const int tid = threadIdx.x, wid = tid >> 6, lane = tid & 63;
  const float rho = rhoarr[K];

  if (blockIdx.y == 0) {
    const float a2 = a2arr[K];
    const float inv = 1.0f / (rho + a2);
    float A[2], zcv[2];
    const int i0 = b * D_ + tid;
#pragma unroll
    for (int j = 0; j < 2; ++j) {
      int i = i0 + j * 256;
      float lp = __logf(p0[i]);
      float prev = (K == 0) ? lp : mun[i];
      zcv[j] = (K == 0) ? 0.f : zC[i];
      A[j] = (rho * prev + a2 * lp - zcv[j]) * inv;
    }
    float m = wmax64(fmaxf(A[0], A[1]));
    if (lane == 0) red[wid] = m;
    __syncthreads();
    float bm = fmaxf(fmaxf(red[0], red[1]), fmaxf(red[2], red[3]));
    float s = wsum64(__expf(A[0] - bm) + __expf(A[1] - bm));
    if (lane == 0) red[4 + wid] = s;
    __syncthreads();
    float lse = bm + __logf(red[4] + red[5] + red[6] + red[7]);
#pragma unroll
    for (int j = 0; j < 2; ++j) {
      int i = i0 + j * 256;
      float mn = A[j] - lse;
      mun[i] = mn;
      if (K <= 1) zC[i] = zcv[j] + rho * __expf(mn);
    }
  } else {
    const float a3 = a3arr[K];
    const float inv = 1.0f / (rho + a3);
    float E[4];
    const int i0 = b * N_ + tid * 4;
#pragma unroll
    for (int j = 0; j < 4; ++j) {
      int i = i0 + j;
      float lq = __logf(q0[i] + EPS_);
      float prev = (K == 0) ? lq : len[i];
      float z2c = (K == 0) ? 0.f : z2C[i];
      E[j] = (rho * prev + a3 * lq - z2c) * inv;
    }
    float m = wmax64(fmaxf(fmaxf(E[0], E[1]), fmaxf(E[2], E[3])));
    if (lane == 0) red[wid] = m;
    __syncthreads();
    float bm = fmaxf(fmaxf(red[0], red[1]), fmaxf(red[2], red[3]));
    float s = 0.f;
#pragma unroll
    for (int j = 0; j < 4; ++j) s += __expf(E[j] - bm);
    s = wsum64(s);
    if (lane == 0) red[4 + wid] = s;
    __syncthreads();
    float lse = bm + __logf(red[4] + red[5] + red[6] + red[7]);
#pragma unroll
    for (int j = 0; j < 4; ++j) {
      int i = i0 + j;
      float ln = E[j] - lse;
      len[i] = ln;
      if (K == 0) z2C[i] = rho * __expf(ln);
    }
  }
}

// ---------------------------------------------------------------------------
extern "C" void kernel_launch(void* const* d_in, const int* in_sizes, int n_in,
                              void* d_out, int out_size, void* d_ws, size_t ws_size,
                              hipStream_t stream)
{
  const float* x    = (const float*)d_in[0];
  const float* p0   = (const float*)d_in[1];
  const float* q0   = (const float*)d_in[2];
  const float* a1   = (const float*)d_in[3];
  const float* a2   = (const float*)d_in[4];
  const float* a3   = (const float*)d_in[5];
  const float* rho  = (const float*)d_in[6];
  const float* mask = (const float*)d_in[7];
  float* out = (float*)d_out;

  float* ws   = (float*)d_ws;
  float* ys   = ws;                               // y'/log_s/w (B,N,D)
  float* z    = ws + NT_;                         // z (B,N,D)
  float* pmax = ws + 2 * NT_;                     // (KCHUNK, NCOL)
  float* psum = pmax + (size_t)KCHUNK * NCOL;
  float* lse1 = psum + (size_t)KCHUNK * NCOL;     // (NCOL)
  float* mun  = lse1 + NCOL;                      // log_mu (B,D)
  float* zC   = mun + (size_t)B_ * D_;
  float* len  = zC  + (size_t)B_ * D_;            // log_eta (B,N)
  float* z2C  = len + (size_t)B_ * N_;

  const dim3 tb(256);
  const dim3 tb1k(1024);
  const dim3 g1(B_ * N_ / 16);                    // k1p: 16 rows/block
  const dim3 gr(NCOL / 256);                      // kred
  const dim3 g2(NCOL / 4 / 256, NCHUNK2);         // k2b: 32 x 64
  const dim3 gl(B_ * N_ / 4);                     // k1last

  // ---- k = 0 ----
  k1p<1><<<g1, tb1k, 0, stream>>>(x, p0, q0, a1, rho, 0, mun, ys, z, pmax, psum);
  kred<<<gr, tb, 0, stream>>>(pmax, psum, lse1);
  k2b<1, 1, 0><<<g2, tb, 0, stream>>>(q0, mask, a1, rho, 0, len, ys, z, lse1);
  small_upd<0><<<dim3(B_, 2), tb, 0, stream>>>(p0, q0, a2, a3, rho, mun, zC, len, z2C);

  // ---- k = 1 ----
  k1p<0><<<g1, tb1k, 0, stream>>>(x, p0, q0, a1, rho, 1, mun, ys, z, pmax, psum);
  kred<<<gr, tb, 0, stream>>>(pmax, psum, lse1);
  k2b<0, 1, 0><<<g2, tb, 0, stream>>>(q0, mask, a1, rho, 1, len, ys, z, lse1);
  small_upd<1><<<dim3(B_, 2), tb, 0, stream>>>(p0, q0, a2, a3, rho, mun, zC, len, z2C);

  // ---- k = 2 (fold z2 into w for the final pass; no z write) ----
  k1p<0><<<g1, tb1k, 0, stream>>>(x, p0, q0, a1, rho, 2, mun, ys, z, pmax, psum);
  kred<<<gr, tb, 0, stream>>>(pmax, psum, lse1);
  k2b<0, 0, 1><<<g2, tb, 0, stream>>>(q0, mask, a1, rho, 2, len, ys, z, lse1);
  small_upd<2><<<dim3(B_, 1), tb, 0, stream>>>(p0, q0, a2, a3, rho, mun, zC, len, z2C);

  // ---- k = 3: out = exp(lmu - lse + x/rho3 + w) * mask ----
  k1last<<<gl, tb, 0, stream>>>(x, mask, rho, mun, ys, out);
}